// Round 10
// baseline (153.942 us; speedup 1.0000x reference)
//
#include <hip/hip_runtime.h>
#include <hip/hip_bf16.h>

#define N_NODES 100000
#define N_EDGES 250000
#define EMB 32
#define TYPES 16
#define R2 100          // num relations
#define SB 1024
#define NB ((N_EDGES + SB - 1) / SB)    // 245
#define NBN ((N_NODES + SB - 1) / SB)   // 98
#define S1 64           // stripes per relation, layer 1
#define S2 64           // stripes per relation, layer 2

typedef __attribute__((ext_vector_type(8))) short short8;
typedef __attribute__((ext_vector_type(4))) float f32x4;

// fp32 -> bf16 bits, round-to-nearest-even
__device__ __forceinline__ unsigned short f2bf_u(float f) {
    unsigned u = __float_as_uint(f);
    u = (u + 0x7fffu + ((u >> 16) & 1u)) >> 16;
    return (unsigned short)u;
}
// unpack bf16 pair from u32
__device__ __forceinline__ float bfl(unsigned u) { return __uint_as_float(u << 16); }
__device__ __forceinline__ float bfh(unsigned u) { return __uint_as_float(u & 0xffff0000u); }

__device__ __forceinline__ int wave_incl_scan(int v, int lane) {
#pragma unroll
    for (int o = 1; o < 64; o <<= 1) {
        int x = __shfl_up(v, o);
        if (lane >= o) v += x;
    }
    return v;
}

// ---------------------------------------------------------------------------
// Pass 1: per-block relation histogram -> counts[b][r]; dcnt atomics;
// fused: entity -> bf16 (2 threads per row, coalesced).
__global__ __launch_bounds__(SB) void hist_conv_kernel(
        const int* __restrict__ etype, const int* __restrict__ edge_dst,
        const float* __restrict__ entity,
        int* __restrict__ counts, int* __restrict__ dcnt,
        unsigned short* __restrict__ ent_bf) {
    __shared__ int lh[R2];
    int t = threadIdx.x, b = blockIdx.x;
    if (t < R2) lh[t] = 0;
    __syncthreads();
    int e = b * SB + t;
    if (e < N_EDGES) {
        atomicAdd(&lh[etype[e]], 1);
        atomicAdd(&dcnt[edge_dst[e]], 1);
    }
    if (e < 2 * N_NODES) {
        int node = e >> 1, half = e & 1;
        const float4* src = (const float4*)(entity + (size_t)node * EMB + half * 16);
        ushort4* dst = (ushort4*)(ent_bf + (size_t)node * EMB + half * 16);
#pragma unroll
        for (int i = 0; i < 4; ++i) {
            float4 v = src[i];
            ushort4 o = { f2bf_u(v.x), f2bf_u(v.y), f2bf_u(v.z), f2bf_u(v.w) };
            dst[i] = o;
        }
    }
    __syncthreads();
    if (t < R2) counts[b * R2 + t] = lh[t];
}

// ---------------------------------------------------------------------------
// Fused scan. Blocks [0,NBN): node-degree block-local exclusive scan.
// Blocks [NBN,NBN+R2): per-relation scan of counts over blocks + W pack.
// Shfl-based: 2 barriers instead of 10.
__global__ __launch_bounds__(SB) void scan_fused_kernel(
        const int* __restrict__ dcnt, int* __restrict__ dstart,
        int* __restrict__ partials,
        const int* __restrict__ counts, int* __restrict__ basem,
        int* __restrict__ total,
        const float* __restrict__ W1, const float* __restrict__ W2,
        unsigned short* __restrict__ pw1, unsigned short* __restrict__ pw2) {
    __shared__ int ws[16];
    int t = threadIdx.x, b = blockIdx.x;
    int lane = t & 63, w = t >> 6;
    if (b < NBN) {
        int i = b * SB + t;
        int v = (i < N_NODES) ? dcnt[i] : 0;
        int inc = wave_incl_scan(v, lane);
        if (lane == 63) ws[w] = inc;
        __syncthreads();
        if (t < 16) {
            int s = ws[t];
            int inc2 = s;
#pragma unroll
            for (int o = 1; o < 16; o <<= 1) {
                int x = __shfl_up(inc2, o);
                if (t >= o) inc2 += x;
            }
            ws[t] = inc2;
        }
        __syncthreads();
        int base = (w == 0) ? 0 : ws[w - 1];
        if (i < N_NODES) dstart[i] = base + inc - v;
        if (t == SB - 1) partials[b] = ws[15];
    } else {
        int r = b - NBN;
        int v = (t < NB) ? counts[t * R2 + r] : 0;
        int inc = wave_incl_scan(v, lane);
        if (lane == 63) ws[w] = inc;
        __syncthreads();
        if (t < 16) {
            int s = ws[t];
            int inc2 = s;
#pragma unroll
            for (int o = 1; o < 16; o <<= 1) {
                int x = __shfl_up(inc2, o);
                if (t >= o) inc2 += x;
            }
            ws[t] = inc2;
        }
        __syncthreads();
        int base = (w == 0) ? 0 : ws[w - 1];
        if (t < NB) basem[t * R2 + r] = base + inc - v;
        if (t == 0) total[r] = ws[15];

        // pack W1 in pair-column order: b0 = col 2n, b1 = col 2n+1; k = q*8+j
        const float* Wr1 = W1 + (size_t)r * (EMB * EMB);
        {
            int l = t >> 4, j = t & 15;
            int n = l & 15, q = l >> 4;
            int k = q * 8 + (j & 7);
            int col = 2 * n + (j >> 3);
            pw1[(size_t)r * 1024 + t] = f2bf_u(Wr1[k * EMB + col]);
        }
        if (t < 512) {
            const float* Wr2 = W2 + (size_t)r * (EMB * TYPES);
            int l = t >> 3, j = t & 7;
            int n = l & 15, q = l >> 4;
            int k = q * 8 + j;
            pw2[(size_t)r * 512 + t] = f2bf_u(Wr2[k * TYPES + n]);
        }
    }
}

// ---------------------------------------------------------------------------
// Scatter: replicated in-block scans of total/partials (shfl), LDS rel-ranks,
// dcur atomics. Block 0 publishes off/psg for downstream kernels.
__global__ __launch_bounds__(SB) void scatter_kernel(
        const int* __restrict__ edge_src, const int* __restrict__ edge_dst,
        const int* __restrict__ etype, const int* __restrict__ src_ids,
        const int* __restrict__ basem, const int* __restrict__ total,
        const int* __restrict__ partials, const int* __restrict__ dstart,
        int* __restrict__ dcur,
        int* __restrict__ sid, int* __restrict__ srcn, int* __restrict__ pdst,
        int* __restrict__ off_g, int* __restrict__ psg) {
    __shared__ int lh[R2];
    __shared__ int off_s[R2 + 1];
    __shared__ int ps_s[NBN];
    int t = threadIdx.x, b = blockIdx.x;
    int lane = t & 63, w = t >> 6;
    if (t < R2) lh[t] = 0;
    if (w == 0) {                                   // scan total[0..R2)
        int a = (lane < R2) ? total[lane] : 0;
        int ai = wave_incl_scan(a, lane);
        int t0 = __shfl(ai, 63);
        int i2 = lane + 64;
        int c = (i2 < R2) ? total[i2] : 0;
        int ci = wave_incl_scan(c, lane) + t0;
        off_s[lane] = ai - a;
        if (i2 < R2) off_s[i2] = ci - c;
        if (i2 == R2 - 1) off_s[R2] = ci;
        if (b == 0) {
            off_g[lane] = ai - a;
            if (i2 < R2) off_g[i2] = ci - c;
            if (i2 == R2 - 1) off_g[R2] = ci;
        }
    } else if (w == 1) {                            // scan partials[0..NBN)
        int a = (lane < NBN) ? partials[lane] : 0;
        int ai = wave_incl_scan(a, lane);
        int t0 = __shfl(ai, 63);
        int i2 = lane + 64;
        int c = (i2 < NBN) ? partials[i2] : 0;
        int ci = wave_incl_scan(c, lane) + t0;
        ps_s[lane] = ai - a;
        if (i2 < NBN) ps_s[i2] = ci - c;
        if (b == 0) {
            psg[lane] = ai - a;
            if (i2 < NBN) psg[i2] = ci - c;
        }
    }
    __syncthreads();
    int e = b * SB + t;
    if (e >= N_EDGES) return;
    int r = etype[e];
    int rank = atomicAdd(&lh[r], 1);
    int relpos = off_s[r] + basem[b * R2 + r] + rank;
    int d = edge_dst[e];
    int drank = atomicAdd(&dcur[d], 1);
    int s = edge_src[e];
    sid[relpos] = src_ids[s];
    srcn[relpos] = s;
    pdst[relpos] = dstart[d] + ps_s[d >> 10] + drank;
}

// ---------------------------------------------------------------------------
// Layer 1: gather A-rows from L2-resident ent_bf; register B-frags (pair-column);
// 2 MFMA/tile; one packed u32 bf16-pair store per row-lane, dst-sorted.
__global__ __launch_bounds__(64) void layer1_kernel(
        const unsigned short* __restrict__ ent_bf,
        const unsigned short* __restrict__ pw1,
        const int* __restrict__ off_g, const int* __restrict__ sid,
        const int* __restrict__ pdst, unsigned int* __restrict__ msg1) {
    int r = blockIdx.x % R2, stripe = blockIdx.x / R2;
    int lo = off_g[r], hi = off_g[r + 1];
    int nT = (hi - lo + 15) >> 4;
    int lane = threadIdx.x;
    int n = lane & 15, q = lane >> 4;
    short8 b0 = *(const short8*)(pw1 + (size_t)r * 1024 + lane * 16);
    short8 b1 = *(const short8*)(pw1 + (size_t)r * 1024 + lane * 16 + 8);
    for (int g = stripe; g < nT; g += S1) {
        int base = lo + g * 16;
        int cl = hi - base;
        int me = n < cl ? n : cl - 1;
        int sv = sid[base + me];
        short8 a = *(const short8*)(ent_bf + (size_t)sv * EMB + q * 8);
        f32x4 c0 = {0.f,0.f,0.f,0.f}, c1 = {0.f,0.f,0.f,0.f};
        c0 = __builtin_amdgcn_mfma_f32_16x16x32_bf16(a, b0, c0, 0, 0, 0);  // cols 2n
        c1 = __builtin_amdgcn_mfma_f32_16x16x32_bf16(a, b1, c1, 0, 0, 0);  // cols 2n+1
#pragma unroll
        for (int i = 0; i < 4; ++i) {
            int row = q * 4 + i;
            if (row < cl) {
                int p = pdst[base + row];
                msg1[(size_t)p * 16 + n] =
                    (unsigned)f2bf_u(c0[i]) | ((unsigned)f2bf_u(c1[i]) << 16);
            }
        }
    }
}

// ---------------------------------------------------------------------------
// Segmented mean + relu -> h1 in bf16 (u32 = col pair 2cp,2cp+1). Sums fp32.
__global__ void reduce1_kernel(const unsigned int* __restrict__ msg1,
                               const int* __restrict__ dstart,
                               const int* __restrict__ psg,
                               const int* __restrict__ dcnt,
                               unsigned int* __restrict__ h1bf) {
    int t = blockIdx.x * blockDim.x + threadIdx.x;   // over N_NODES*16
    if (t >= N_NODES * 16) return;
    int nn = t >> 4, cp = t & 15;
    int s = dstart[nn] + psg[nn >> 10];
    int cnt = dcnt[nn];
    float sx = 0.f, sy = 0.f;
    for (int k = 0; k < cnt; ++k) {
        unsigned v = msg1[(size_t)(s + k) * 16 + cp];
        sx += bfl(v); sy += bfh(v);
    }
    float inv = 1.0f / fmaxf((float)cnt, 1.0f);
    unsigned lo = f2bf_u(fmaxf(sx * inv, 0.f));
    unsigned hi = f2bf_u(fmaxf(sy * inv, 0.f));
    h1bf[t] = lo | (hi << 16);
}

// ---------------------------------------------------------------------------
// Layer 2: gather bf16 h1 rows (16B/lane), 1 MFMA/tile, store bf16 msg2 dst-sorted.
__global__ __launch_bounds__(64) void layer2_kernel(
        const unsigned short* __restrict__ h1bf,
        const unsigned short* __restrict__ pw2,
        const int* __restrict__ off_g, const int* __restrict__ srcn,
        const int* __restrict__ pdst, unsigned short* __restrict__ msg2) {
    int r = blockIdx.x % R2, stripe = blockIdx.x / R2;
    int lo = off_g[r], hi = off_g[r + 1];
    int nT = (hi - lo + 15) >> 4;
    int lane = threadIdx.x;
    int n = lane & 15, q = lane >> 4;
    short8 b = *(const short8*)(pw2 + (size_t)r * 512 + lane * 8);
    for (int g = stripe; g < nT; g += S2) {
        int base = lo + g * 16;
        int cl = hi - base;
        int me = n < cl ? n : cl - 1;
        int s = srcn[base + me];
        short8 a = *(const short8*)(h1bf + (size_t)s * EMB + q * 8);
        f32x4 c = {0.f,0.f,0.f,0.f};
        c = __builtin_amdgcn_mfma_f32_16x16x32_bf16(a, b, c, 0, 0, 0);
#pragma unroll
        for (int i = 0; i < 4; ++i) {
            int row = q * 4 + i;
            if (row < cl) {
                int p = pdst[base + row];
                msg2[(size_t)p * TYPES + n] = f2bf_u(c[i]);
            }
        }
    }
}

// ---------------------------------------------------------------------------
// Segmented mean + PonderNet head, fused; writes final fp32 output.
__global__ void reduce2_head_kernel(const unsigned int* __restrict__ msg2,
                                    const int* __restrict__ dstart,
                                    const int* __restrict__ psg,
                                    const int* __restrict__ dcnt,
                                    const float* __restrict__ lw,
                                    const float* __restrict__ lb,
                                    float* __restrict__ out) {
    int nn = blockIdx.x * blockDim.x + threadIdx.x;
    if (nn >= N_NODES) return;
    int s = dstart[nn] + psg[nn >> 10];
    int cnt = dcnt[nn];

    float h[TYPES];
#pragma unroll
    for (int j = 0; j < TYPES; ++j) h[j] = 0.f;
    for (int k = 0; k < cnt; ++k) {
        const uint4* row = (const uint4*)(msg2 + (size_t)(s + k) * 8);
        uint4 A = row[0], B = row[1];
        h[0] += bfl(A.x);  h[1] += bfh(A.x);  h[2] += bfl(A.y);  h[3] += bfh(A.y);
        h[4] += bfl(A.z);  h[5] += bfh(A.z);  h[6] += bfl(A.w);  h[7] += bfh(A.w);
        h[8] += bfl(B.x);  h[9] += bfh(B.x);  h[10] += bfl(B.y); h[11] += bfh(B.y);
        h[12] += bfl(B.z); h[13] += bfh(B.z); h[14] += bfl(B.w); h[15] += bfh(B.w);
    }
    float inv = 1.0f / fmaxf((float)cnt, 1.0f);
    float dot = 0.f;
#pragma unroll
    for (int j = 0; j < TYPES; ++j) { h[j] *= inv; dot += h[j] * lw[j]; }
    dot += lb[0];
    float lam = 1.0f / (1.0f + expf(-dot));

    float4* y0 = (float4*)(out + (size_t)nn * TYPES);
    float4* y1 = (float4*)(out + (size_t)N_NODES * TYPES + (size_t)nn * TYPES);
#pragma unroll
    for (int j = 0; j < 4; ++j) {
        float4 v = { h[4*j], h[4*j+1], h[4*j+2], h[4*j+3] };
        y0[j] = v; y1[j] = v;
    }
    out[(size_t)2 * N_NODES * TYPES + nn] = lam;
    out[(size_t)2 * N_NODES * TYPES + N_NODES + nn] = 1.0f - lam;
}

// ---------------------------------------------------------------------------
extern "C" void kernel_launch(void* const* d_in, const int* in_sizes, int n_in,
                              void* d_out, int out_size, void* d_ws, size_t ws_size,
                              hipStream_t stream) {
    const float* entity = (const float*)d_in[0];
    const float* W1     = (const float*)d_in[1];
    const float* W2     = (const float*)d_in[2];
    const float* lw     = (const float*)d_in[3];
    const float* lb     = (const float*)d_in[4];
    const int* src_ids  = (const int*)d_in[5];
    const int* edge_src = (const int*)d_in[6];
    const int* edge_dst = (const int*)d_in[7];
    const int* etype    = (const int*)d_in[8];
    float* out = (float*)d_out;

    // ws layout (u32 units)
    unsigned int* W = (unsigned int*)d_ws;
    int* dcnt      = (int*)(W + 0);            // 100000 (zeroed)
    int* dcur      = (int*)(W + 100000);       // 100000 (zeroed)
    int* dstart    = (int*)(W + 200000);       // 100008
    int* partials  = (int*)(W + 300008);       // 128 (raw block sums)
    int* counts    = (int*)(W + 300136);       // 24500
    int* basem     = (int*)(W + 324636);       // 24500
    int* total     = (int*)(W + 349136);       // 128
    int* off_g     = (int*)(W + 349264);       // 128
    int* psg       = (int*)(W + 349392);       // 128
    int* sid       = (int*)(W + 349520);       // 250000
    int* srcn      = (int*)(W + 599520);       // 250000
    int* pdst      = (int*)(W + 849520);       // 250000
    unsigned short* ent_bf = (unsigned short*)(W + 1099520); // 1.6M u32
    unsigned short* pw1    = (unsigned short*)(W + 2699520); // 51200 u32
    unsigned short* pw2    = (unsigned short*)(W + 2750720); // 25600 u32
    unsigned int* msg1     = (unsigned int*)(W + 2776320);   // 4M u32
    unsigned int* h1bf     = (unsigned int*)(W + 6776320);   // 1.6M u32
    unsigned int* msg2     = (unsigned int*)(W + 8376320);   // 2M u32  -> ~41.5 MB

    (void)hipMemsetAsync(d_ws, 0, 200000 * sizeof(int), stream);   // dcnt + dcur

    hist_conv_kernel<<<NB, SB, 0, stream>>>(etype, edge_dst, entity,
                                            counts, dcnt, ent_bf);
    scan_fused_kernel<<<NBN + R2, SB, 0, stream>>>(dcnt, dstart, partials,
                                                   counts, basem, total,
                                                   W1, W2, pw1, pw2);
    scatter_kernel<<<NB, SB, 0, stream>>>(edge_src, edge_dst, etype, src_ids,
                                          basem, total, partials, dstart, dcur,
                                          sid, srcn, pdst, off_g, psg);
    layer1_kernel<<<R2 * S1, 64, 0, stream>>>(ent_bf, pw1, off_g, sid, pdst, msg1);
    reduce1_kernel<<<(N_NODES * 16 + 255) / 256, 256, 0, stream>>>(
        msg1, dstart, psg, dcnt, h1bf);
    layer2_kernel<<<R2 * S2, 64, 0, stream>>>((const unsigned short*)h1bf, pw2,
                                              off_g, srcn, pdst,
                                              (unsigned short*)msg2);
    reduce2_head_kernel<<<(N_NODES + 255) / 256, 256, 0, stream>>>(
        msg2, dstart, psg, dcnt, lw, lb, out);
}